// Round 1
// baseline (488.538 us; speedup 1.0000x reference)
//
#include <hip/hip_runtime.h>
#include <hip/hip_bf16.h>
#include <stdint.h>

#define PI_F 3.14159265358979f
#define EMBR 0.0275f
#define BATCH 1024
#define DIM 512
#define D2 1024
#define HID 2048
#define NB 30
#define K1 (NB * D2)          // 30720

using short8 = __attribute__((ext_vector_type(8))) short;
using f32x4  = __attribute__((ext_vector_type(4))) float;

// s_waitcnt: vmcnt lo [3:0], expcnt [6:4]=7 (ignore), lgkmcnt [11:8]=0xF (ignore), vmcnt hi [15:14]
#define WAITVM(N) __builtin_amdgcn_s_waitcnt(((N) & 0xF) | (((N) >> 4) << 14) | (0x7 << 4) | (0xF << 8))

__device__ __forceinline__ ushort f2bf(float f) {
  uint32_t u = __builtin_bit_cast(uint32_t, f);
  u += 0x7fffu + ((u >> 16) & 1u);   // RNE
  return (ushort)(u >> 16);
}

// async global->LDS, 16B per lane; LDS dest = wave-uniform base + lane*16
__device__ __forceinline__ void gld_lds16(const void* g, void* l) {
  __builtin_amdgcn_global_load_lds(
      (const __attribute__((address_space(1))) uint32_t*)(uintptr_t)g,
      (__attribute__((address_space(3))) uint32_t*)(uintptr_t)l, 16, 0, 0);
}

// ============ mega prep: rel_base transpose+cvt | prep | weight cvts ============
#define TR_BLKS 7680                    // (D2/64=16) x (K1/64=480)
#define PREP_BLKS 1024
#define W1F4 (HID * D2 / 4)             // 524288
#define W2F4 (HID * HID / 4)            // 1048576
#define W0F4 (D2 * HID / 4)             // 524288
#define WA1F4 (DIM * D2 / 4)            // 131072
#define WA2F4 (D2 * DIM / 4)            // 131072
#define CVT_BLKS ((W1F4 + W2F4 + W0F4 + WA1F4 + WA2F4) / 256)  // 9216

__global__ __launch_bounds__(256) void mega_prep(
    const float* __restrict__ rel_base, ushort* __restrict__ RBt,
    const float* __restrict__ axis, const float* __restrict__ argp,
    const int* __restrict__ rel, const float* __restrict__ rel_att,
    const float* __restrict__ rel_ax, const float* __restrict__ rel_ar,
    float* __restrict__ attb, ushort* __restrict__ Ebf, ushort* __restrict__ h0,
    const float* __restrict__ W1, const float* __restrict__ W2,
    const float* __restrict__ W0, const float* __restrict__ Wa1,
    const float* __restrict__ Wa2,
    ushort* __restrict__ W1b, ushort* __restrict__ W2b, ushort* __restrict__ W0b,
    ushort* __restrict__ Wa1b, ushort* __restrict__ Wa2b) {
  __shared__ ushort ts[64][68];
  const int bid = blockIdx.x, t = threadIdx.x;
  if (bid < TR_BLKS) {
    // transpose+cvt of rel_base: src (r*D2+i) x o fp32 -> dst (r*D2+o) x i bf16
    // (per-base 1024x1024 transpose; dst rows n = r*1024+o, dst cols = i)
    const int c0 = (bid & 15) * 64, r0 = (bid >> 4) * 64;
    const int tc = (t & 15) * 4;
    const int tr = t >> 4;
#pragma unroll
    for (int j = 0; j < 4; ++j) {
      const int r = tr + j * 16;
      float4 v = *(const float4*)&rel_base[(size_t)(r0 + r) * D2 + c0 + tc];
      ushort4 o;
      o.x = f2bf(v.x); o.y = f2bf(v.y); o.z = f2bf(v.z); o.w = f2bf(v.w);
      *(ushort4*)&ts[r][tc] = o;
    }
    __syncthreads();
#pragma unroll
    for (int j = 0; j < 4; ++j) {
      const int c = tr + j * 16;
      ushort4 v;
      v.x = ts[tc + 0][c]; v.y = ts[tc + 1][c];
      v.z = ts[tc + 2][c]; v.w = ts[tc + 3][c];
      // r0 is 64-aligned -> base (r0>>10) constant per block; i0 = r0&1023
      *(ushort4*)&RBt[((size_t)((r0 & ~1023) + c0 + c)) * 1024 + (r0 & 1023) + tc] = v;
    }
  } else if (bid < TR_BLKS + PREP_BLKS) {
    const int b = bid - TR_BLKS;
    const int ri = rel[b];
    if (t < NB)
      attb[b * 32 + t] = tanhf(rel_att[ri * NB + t] * (1.f / EMBR)) * PI_F;
    for (int i = t; i < DIM; i += 256) {
      const float ax = axis[(size_t)b * DIM + i];
      const float ag = argp[(size_t)b * DIM + i];
      Ebf[(size_t)b * D2 + i]       = f2bf(ax);
      Ebf[(size_t)b * D2 + DIM + i] = f2bf(ag);
      const float ra = rel_ax[(size_t)ri * DIM + i];
      const float rg = rel_ar[(size_t)ri * DIM + i];
      h0[(size_t)b * D2 + i] = f2bf(ax + tanhf(ra * (1.f / EMBR)) * PI_F);
      h0[(size_t)b * D2 + DIM + i] =
          f2bf(ag + tanhf(2.f * rg * (1.f / EMBR)) * (PI_F * 0.5f) + PI_F * 0.5f);
    }
  } else {
    int i = (bid - TR_BLKS - PREP_BLKS) * 256 + t;
    const float* s; ushort* d;
    if (i < W1F4) { s = W1; d = W1b; }
    else if ((i -= W1F4) < W2F4) { s = W2; d = W2b; }
    else if ((i -= W2F4) < W0F4) { s = W0; d = W0b; }
    else if ((i -= W0F4) < WA1F4) { s = Wa1; d = Wa1b; }
    else { i -= WA1F4; s = Wa2; d = Wa2b; }
    float4 v = ((const float4*)s)[i];
    ushort4 o;
    o.x = f2bf(v.x); o.y = f2bf(v.y); o.z = f2bf(v.z); o.w = f2bf(v.w);
    ((ushort4*)d)[i] = o;
  }
}

// ======= pipelined NT GEMM: C[m,n] = sum_k A[m,k]*Bt[n,k]; depth-3 prefetch =======
// EPI 1: bf16 out = relu(acc + bias[n]);  EPI 2: fp32 out = acc + bias[n]
template <int EPI>
__global__ __launch_bounds__(256, 2) void gemm_nt(
    const ushort* __restrict__ A, const ushort* __restrict__ Bt,
    const float* __restrict__ bias, float* __restrict__ Cf,
    ushort* __restrict__ Cb, int M, int N, int K) {
  __shared__ ushort As[4][128 * 32];
  __shared__ ushort Bs[4][128 * 32];
  const int tid  = threadIdx.x;
  const int lane = tid & 63, wave = tid >> 6;
  const int wm = wave >> 1, wn = wave & 1;
  const int lrow = lane & 15, quad = lane >> 4;
  const int m0 = blockIdx.y * 128, n0 = blockIdx.x * 128;
  const int T = K >> 5;

  const int rr = lane >> 2;
  const int eo = (lane & 3) * 8;
  const int c1 = wave, c2 = wave + 4;
  const ushort* Ag1 = A  + (size_t)(m0 + c1 * 16 + rr) * K + eo;
  const ushort* Ag2 = A  + (size_t)(m0 + c2 * 16 + rr) * K + eo;
  const ushort* Bg1 = Bt + (size_t)(n0 + c1 * 16 + rr) * K + eo;
  const ushort* Bg2 = Bt + (size_t)(n0 + c2 * 16 + rr) * K + eo;

  auto issue = [&](int slot) {
    const int t  = (slot < T - 1) ? slot : T - 1;
    const int bf = slot & 3;
    const int kk = t << 5;
    gld_lds16(Ag1 + kk, &As[bf][c1 * 512]);
    gld_lds16(Ag2 + kk, &As[bf][c2 * 512]);
    gld_lds16(Bg1 + kk, &Bs[bf][c1 * 512]);
    gld_lds16(Bg2 + kk, &Bs[bf][c2 * 512]);
  };

  f32x4 acc[4][4] = {};
  issue(0); issue(1); issue(2);

  for (int t = 0; t < T; ++t) {
    WAITVM(8);                          // tile t's 4 loads done; 2 batches in flight
    __builtin_amdgcn_s_barrier();
    issue(t + 3);
    const ushort* as = As[t & 3];
    const ushort* bs = Bs[t & 3];
    short8 af[4], bq[4];
#pragma unroll
    for (int i = 0; i < 4; ++i) {
      af[i] = *(const short8*)&as[(wm * 64 + i * 16 + lrow) * 32 + quad * 8];
      bq[i] = *(const short8*)&bs[(wn * 64 + i * 16 + lrow) * 32 + quad * 8];
    }
#pragma unroll
    for (int mi = 0; mi < 4; ++mi)
#pragma unroll
      for (int ni = 0; ni < 4; ++ni)
        acc[mi][ni] = __builtin_amdgcn_mfma_f32_16x16x32_bf16(
            af[mi], bq[ni], acc[mi][ni], 0, 0, 0);
  }
  WAITVM(0);                            // drain clamped prefetches before LDS dealloc

  const int colBase = n0 + wn * 64;
  const int rowBase = m0 + wm * 64;
#pragma unroll
  for (int mi = 0; mi < 4; ++mi) {
#pragma unroll
    for (int ni = 0; ni < 4; ++ni) {
      const int col  = colBase + ni * 16 + lrow;
      const int row0 = rowBase + mi * 16 + quad * 4;
      const float bv = bias[col];
      if (EPI == 1) {
#pragma unroll
        for (int g = 0; g < 4; ++g)
          Cb[(size_t)(row0 + g) * N + col] = f2bf(fmaxf(acc[mi][ni][g] + bv, 0.f));
      } else {
#pragma unroll
        for (int g = 0; g < 4; ++g)
          Cf[(size_t)(row0 + g) * N + col] = acc[mi][ni][g] + bv;
      }
    }
  }
}

// ==== rtrans as ONE plain NT GEMM: tmp[b, r*1024+o] = E[b,:]·RBt2[r*1024+o,:] ====
// M=1024, N=30720, K=1024. Each 256-col block lies inside one base r (256|1024),
// so att-weighting is a per-block epilogue: atomicAdd(att[b,r]*acc) into outrt.
// Geometry: BM=128 x BN=256, wave tile 64x128 (43.7 FLOP/LDS-byte vs 32.8 before),
// 3 LDS buffers (72 KB -> 2 blocks/CU), depth-2 counted-vmcnt prefetch.
__global__ __launch_bounds__(256, 2) void gemm_rt2(
    const ushort* __restrict__ A,   // Ebf  (1024 x 1024)
    const ushort* __restrict__ Bt,  // RBt2 (30720 x 1024)
    const float* __restrict__ attb, // (B, 32)
    float* __restrict__ outrt) {    // (B, 1024), pre-zeroed
  __shared__ ushort As[3][128 * 32];
  __shared__ ushort Bs[3][256 * 32];
  const int tid  = threadIdx.x;
  const int lane = tid & 63, wave = tid >> 6;
  const int wm = wave >> 1, wn = wave & 1;
  const int lrow = lane & 15, quad = lane >> 4;
  const int n0 = blockIdx.x * 256, m0 = blockIdx.y * 128;
  const int r  = n0 >> 10;              // base index, uniform per block
  const int K = 1024, T = 32;

  const int rr = lane >> 2;
  const int eo = (lane & 3) * 8;
  const ushort* Ag0 = A  + (size_t)(m0 +   0 + wave * 16 + rr) * K + eo;
  const ushort* Ag1 = A  + (size_t)(m0 +  64 + wave * 16 + rr) * K + eo;
  const ushort* Bg0 = Bt + (size_t)(n0 +   0 + wave * 16 + rr) * K + eo;
  const ushort* Bg1 = Bt + (size_t)(n0 +  64 + wave * 16 + rr) * K + eo;
  const ushort* Bg2 = Bt + (size_t)(n0 + 128 + wave * 16 + rr) * K + eo;
  const ushort* Bg3 = Bt + (size_t)(n0 + 192 + wave * 16 + rr) * K + eo;

  auto issue = [&](int slot) {
    const int t  = (slot < T - 1) ? slot : T - 1;  // clamp: keeps vmcnt bookkeeping exact
    const int bf = slot % 3;
    const int kk = t << 5;
    gld_lds16(Ag0 + kk, &As[bf][(  0 + wave * 16) * 32]);
    gld_lds16(Ag1 + kk, &As[bf][( 64 + wave * 16) * 32]);
    gld_lds16(Bg0 + kk, &Bs[bf][(  0 + wave * 16) * 32]);
    gld_lds16(Bg1 + kk, &Bs[bf][( 64 + wave * 16) * 32]);
    gld_lds16(Bg2 + kk, &Bs[bf][(128 + wave * 16) * 32]);
    gld_lds16(Bg3 + kk, &Bs[bf][(192 + wave * 16) * 32]);
  };

  f32x4 acc[4][8] = {};
  issue(0); issue(1);

  for (int t = 0; t < T; ++t) {
    WAITVM(6);                          // tile t's 6 loads done; tile t+1 in flight
    __builtin_amdgcn_s_barrier();
    issue(t + 2);
    const ushort* as = As[t % 3];
    const ushort* bs = Bs[t % 3];
    short8 af[4], bq[8];
#pragma unroll
    for (int i = 0; i < 4; ++i)
      af[i] = *(const short8*)&as[(wm * 64 + i * 16 + lrow) * 32 + quad * 8];
#pragma unroll
    for (int i = 0; i < 8; ++i)
      bq[i] = *(const short8*)&bs[(wn * 128 + i * 16 + lrow) * 32 + quad * 8];
#pragma unroll
    for (int mi = 0; mi < 4; ++mi)
#pragma unroll
      for (int ni = 0; ni < 8; ++ni)
        acc[mi][ni] = __builtin_amdgcn_mfma_f32_16x16x32_bf16(
            af[mi], bq[ni], acc[mi][ni], 0, 0, 0);
  }
  WAITVM(0);                            // drain clamped prefetches

  const int colBase = n0 + wn * 128;
  const int rowBase = m0 + wm * 64;
#pragma unroll
  for (int mi = 0; mi < 4; ++mi) {
#pragma unroll
    for (int ni = 0; ni < 8; ++ni) {
      const int col = colBase + ni * 16 + lrow;
      const int o   = col & 1023;
      const int row0 = rowBase + mi * 16 + quad * 4;
#pragma unroll
      for (int g = 0; g < 4; ++g) {
        const float s = attb[(row0 + g) * 32 + r];
        unsafeAtomicAdd(&outrt[(size_t)(row0 + g) * D2 + o], s * acc[mi][ni][g]);
      }
    }
  }
}

// ------- att@rel_bias + LayerNorm of atomic-accumulated rtrans -> xrt, Xb row -------
__global__ __launch_bounds__(256) void reduce_ln_rt(
    const float* __restrict__ outrt, const float* __restrict__ att,
    const float* __restrict__ rel_bias, float* __restrict__ xf,
    ushort* __restrict__ Xb) {
  const int b = blockIdx.x, t = threadIdx.x;
  __shared__ float attS[NB];
  __shared__ float sa[4], sb[4];
  if (t < NB) attS[t] = att[b * 32 + t];
  __syncthreads();
  float v[4], sum = 0.f, sq = 0.f;
#pragma unroll
  for (int j = 0; j < 4; ++j) {
    const int o = j * 256 + t;
    float acc = outrt[(size_t)b * D2 + o];
    float bias = 0.f;
    for (int r = 0; r < NB; ++r) bias += attS[r] * rel_bias[r * D2 + o];
    acc += bias;
    v[j] = acc; sum += acc; sq += acc * acc;
  }
  const int lane = t & 63, wv = t >> 6;
  for (int off = 32; off > 0; off >>= 1) {
    sum += __shfl_down(sum, off, 64);
    sq  += __shfl_down(sq, off, 64);
  }
  if (lane == 0) { sa[wv] = sum; sb[wv] = sq; }
  __syncthreads();
  const float S = sa[0] + sa[1] + sa[2] + sa[3];
  const float Q = sb[0] + sb[1] + sb[2] + sb[3];
  const float mean = S / D2;
  const float inv = rsqrtf(fmaxf(Q / D2 - mean * mean, 0.f) + 1e-5f);
#pragma unroll
  for (int j = 0; j < 4; ++j) {
    const int o = j * 256 + t;
    const float y = (v[j] - mean) * inv;
    xf[(size_t)b * D2 + o] = y;
    Xb[(size_t)b * D2 + o] = f2bf(y);
  }
}

// ---------------- row LayerNorm (mlp branch) ----------------
__global__ __launch_bounds__(256) void ln_rows(
    const float* __restrict__ G, float* __restrict__ xf, ushort* __restrict__ Xb) {
  const int b = blockIdx.x, t = threadIdx.x;
  __shared__ float sa[4], sb[4];
  float v[4], sum = 0.f, sq = 0.f;
#pragma unroll
  for (int j = 0; j < 4; ++j) {
    const int o = j * 256 + t;
    v[j] = G[(size_t)b * D2 + o];
    sum += v[j]; sq += v[j] * v[j];
  }
  const int lane = t & 63, wv = t >> 6;
  for (int off = 32; off > 0; off >>= 1) {
    sum += __shfl_down(sum, off, 64);
    sq  += __shfl_down(sq, off, 64);
  }
  if (lane == 0) { sa[wv] = sum; sb[wv] = sq; }
  __syncthreads();
  const float S = sa[0] + sa[1] + sa[2] + sa[3];
  const float Q = sb[0] + sb[1] + sb[2] + sb[3];
  const float mean = S / D2;
  const float inv = rsqrtf(fmaxf(Q / D2 - mean * mean, 0.f) + 1e-5f);
#pragma unroll
  for (int j = 0; j < 4; ++j) {
    const int o = j * 256 + t;
    const float y = (v[j] - mean) * inv;
    xf[(size_t)b * D2 + o] = y;
    Xb[(size_t)b * D2 + o] = f2bf(y);
  }
}

// -------- softmax over 2 branches + merge + final activations -> out (fp32) --------
__global__ __launch_bounds__(256) void fuse_out(
    const float* __restrict__ L, const float* __restrict__ xrt,
    const float* __restrict__ xml, float* __restrict__ out) {
  const int b = blockIdx.x, t = threadIdx.x;
#pragma unroll
  for (int j = 0; j < 4; ++j) {
    const int o = j * 256 + t;
    const float l0 = L[(size_t)b * D2 + o];
    const float l1 = L[(size_t)(BATCH + b) * D2 + o];
    const float w0 = 1.f / (1.f + expf(l1 - l0));
    const float m = w0 * xrt[(size_t)b * D2 + o] +
                    (1.f - w0) * xml[(size_t)b * D2 + o];
    if (o < DIM)
      out[(size_t)b * DIM + o] = tanhf(m) * PI_F;
    else
      out[(size_t)BATCH * DIM + (size_t)b * DIM + (o - DIM)] =
          tanhf(2.f * m) * (PI_F * 0.5f) + PI_F * 0.5f;
  }
}

extern "C" void kernel_launch(void* const* d_in, const int* in_sizes, int n_in,
                              void* d_out, int out_size, void* d_ws, size_t ws_size,
                              hipStream_t stream) {
  (void)in_sizes; (void)n_in; (void)out_size; (void)ws_size;
  const float* s_axis   = (const float*)d_in[0];
  const float* s_arg    = (const float*)d_in[1];
  const int*   rel      = (const int*)d_in[2];
  const float* rel_base = (const float*)d_in[3];
  const float* rel_att  = (const float*)d_in[4];
  const float* rel_bias = (const float*)d_in[5];
  const float* rel_ax_e = (const float*)d_in[6];
  const float* rel_ar_e = (const float*)d_in[7];
  const float* W1 = (const float*)d_in[8];
  const float* b1 = (const float*)d_in[9];
  const float* W2 = (const float*)d_in[10];
  const float* b2 = (const float*)d_in[11];
  const float* W0 = (const float*)d_in[12];
  const float* b0 = (const float*)d_in[13];
  const float* Wa1 = (const float*)d_in[14];
  const float* ba1 = (const float*)d_in[15];
  const float* Wa2 = (const float*)d_in[16];
  const float* ba2 = (const float*)d_in[17];

  char* ws = (char*)d_ws;
  size_t off = 0;
  ushort* RBt2 = (ushort*)(ws + off); off += (size_t)K1 * D2 * 2;            // 63 MB
  float*  outrt= (float*)(ws + off);  off += (size_t)BATCH * D2 * 4;         // 4 MB
  ushort* Ebf  = (ushort*)(ws + off); off += (size_t)BATCH * D2 * 2;
  ushort* W1b  = (ushort*)(ws + off); off += (size_t)HID * D2 * 2;
  ushort* W2b  = (ushort*)(ws + off); off += (size_t)HID * HID * 2;
  ushort* W0b  = (ushort*)(ws + off); off += (size_t)D2 * HID * 2;
  ushort* Wa1b = (ushort*)(ws + off); off += (size_t)DIM * D2 * 2;
  ushort* Wa2b = (ushort*)(ws + off); off += (size_t)D2 * DIM * 2;
  ushort* h0   = (ushort*)(ws + off); off += (size_t)BATCH * D2 * 2;
  ushort* Xb   = (ushort*)(ws + off); off += (size_t)2 * BATCH * D2 * 2;
  float*  xrt  = (float*)(ws + off);  off += (size_t)BATCH * D2 * 4;
  float*  xml  = (float*)(ws + off);  off += (size_t)BATCH * 32 * 4 + (size_t)BATCH * D2 * 4;
  float*  attb = (float*)(ws + off);  off += (size_t)BATCH * 32 * 4;
  // late buffers alias RBt2 (dead after gemm_rt2); 22 MB <= 63 MB
  char* ali = (char*)RBt2;
  ushort* H1  = (ushort*)ali; ali += (size_t)BATCH * HID * 2;
  ushort* H2  = (ushort*)ali; ali += (size_t)BATCH * HID * 2;
  float*  G0  = (float*)ali;  ali += (size_t)BATCH * D2 * 4;
  ushort* Aat = (ushort*)ali; ali += (size_t)2 * BATCH * DIM * 2;
  float*  Lg  = (float*)ali;  ali += (size_t)2 * BATCH * D2 * 4;

  hipMemsetAsync(outrt, 0, (size_t)BATCH * D2 * 4, stream);
  mega_prep<<<TR_BLKS + PREP_BLKS + CVT_BLKS, 256, 0, stream>>>(
      rel_base, RBt2, s_axis, s_arg, rel, rel_att, rel_ax_e, rel_ar_e,
      attb, Ebf, h0, W1, W2, W0, Wa1, Wa2, W1b, W2b, W0b, Wa1b, Wa2b);
  gemm_rt2<<<dim3(K1 / 256, BATCH / 128), 256, 0, stream>>>(
      Ebf, RBt2, attb, outrt);
  reduce_ln_rt<<<BATCH, 256, 0, stream>>>(outrt, attb, rel_bias, xrt, Xb);
  gemm_nt<1><<<dim3(HID / 128, BATCH / 128), 256, 0, stream>>>(
      h0, W1b, b1, nullptr, H1, BATCH, HID, D2);
  gemm_nt<1><<<dim3(HID / 128, BATCH / 128), 256, 0, stream>>>(
      H1, W2b, b2, nullptr, H2, BATCH, HID, HID);
  gemm_nt<2><<<dim3(D2 / 128, BATCH / 128), 256, 0, stream>>>(
      H2, W0b, b0, G0, nullptr, BATCH, D2, HID);
  ln_rows<<<BATCH, 256, 0, stream>>>(G0, xml, Xb + (size_t)BATCH * D2);
  gemm_nt<1><<<dim3(DIM / 128, 2 * BATCH / 128), 256, 0, stream>>>(
      Xb, Wa1b, ba1, nullptr, Aat, 2 * BATCH, DIM, D2);
  gemm_nt<2><<<dim3(D2 / 128, 2 * BATCH / 128), 256, 0, stream>>>(
      Aat, Wa2b, ba2, Lg, nullptr, 2 * BATCH, D2, DIM);
  fuse_out<<<BATCH, 256, 0, stream>>>(Lg, xrt, xml, (float*)d_out);
}

// Round 8
// 416.927 us; speedup vs baseline: 1.1718x; 1.1718x over previous
//
#include <hip/hip_runtime.h>
#include <hip/hip_bf16.h>
#include <stdint.h>

#define PI_F 3.14159265358979f
#define EMBR 0.0275f
#define BATCH 1024
#define DIM 512
#define D2 1024
#define HID 2048
#define NB 30
#define K1 (NB * D2)          // 30720
#define NZ 8                  // i-chunk slices for rtrans GEMM

using short8 = __attribute__((ext_vector_type(8))) short;
using f32x4  = __attribute__((ext_vector_type(4))) float;

// s_waitcnt: vmcnt lo [3:0], expcnt [6:4]=7 (ignore), lgkmcnt [11:8]=0xF (ignore), vmcnt hi [15:14]
#define WAITVM(N) __builtin_amdgcn_s_waitcnt(((N) & 0xF) | (((N) >> 4) << 14) | (0x7 << 4) | (0xF << 8))
#define SCHED_FENCE() __builtin_amdgcn_sched_barrier(0)

__device__ __forceinline__ ushort f2bf(float f) {
  uint32_t u = __builtin_bit_cast(uint32_t, f);
  u += 0x7fffu + ((u >> 16) & 1u);   // RNE
  return (ushort)(u >> 16);
}

// async global->LDS, 16B per lane; LDS dest = wave-uniform base + lane*16
__device__ __forceinline__ void gld_lds16(const void* g, void* l) {
  __builtin_amdgcn_global_load_lds(
      (const __attribute__((address_space(1))) uint32_t*)(uintptr_t)g,
      (__attribute__((address_space(3))) uint32_t*)(uintptr_t)l, 16, 0, 0);
}

// ============ mega prep: rel_base transpose+cvt | prep | weight cvts ============
#define TR_BLKS 7680                    // (D2/64=16) x (K1/64=480)
#define PREP_BLKS 1024
#define W1F4 (HID * D2 / 4)             // 524288
#define W2F4 (HID * HID / 4)            // 1048576
#define W0F4 (D2 * HID / 4)             // 524288
#define WA1F4 (DIM * D2 / 4)            // 131072
#define WA2F4 (D2 * DIM / 4)            // 131072
#define CVT_BLKS ((W1F4 + W2F4 + W0F4 + WA1F4 + WA2F4) / 256)  // 9216

__global__ __launch_bounds__(256) void mega_prep(
    const float* __restrict__ rel_base, ushort* __restrict__ RBt,
    const float* __restrict__ axis, const float* __restrict__ argp,
    const int* __restrict__ rel, const float* __restrict__ rel_att,
    const float* __restrict__ rel_ax, const float* __restrict__ rel_ar,
    float* __restrict__ attb, ushort* __restrict__ Ebf, ushort* __restrict__ h0,
    const float* __restrict__ W1, const float* __restrict__ W2,
    const float* __restrict__ W0, const float* __restrict__ Wa1,
    const float* __restrict__ Wa2,
    ushort* __restrict__ W1b, ushort* __restrict__ W2b, ushort* __restrict__ W0b,
    ushort* __restrict__ Wa1b, ushort* __restrict__ Wa2b) {
  __shared__ ushort ts[64][68];
  const int bid = blockIdx.x, t = threadIdx.x;
  if (bid < TR_BLKS) {
    // transpose+cvt of rel_base: src K1 x D2 fp32 -> dst D2 x K1 bf16
    const int c0 = (bid & 15) * 64, r0 = (bid >> 4) * 64;
    const int tc = (t & 15) * 4;
    const int tr = t >> 4;
#pragma unroll
    for (int j = 0; j < 4; ++j) {
      const int r = tr + j * 16;
      float4 v = *(const float4*)&rel_base[(size_t)(r0 + r) * D2 + c0 + tc];
      ushort4 o;
      o.x = f2bf(v.x); o.y = f2bf(v.y); o.z = f2bf(v.z); o.w = f2bf(v.w);
      *(ushort4*)&ts[r][tc] = o;
    }
    __syncthreads();
#pragma unroll
    for (int j = 0; j < 4; ++j) {
      const int c = tr + j * 16;
      ushort4 v;
      v.x = ts[tc + 0][c]; v.y = ts[tc + 1][c];
      v.z = ts[tc + 2][c]; v.w = ts[tc + 3][c];
      *(ushort4*)&RBt[(size_t)(c0 + c) * K1 + r0 + tc] = v;
    }
  } else if (bid < TR_BLKS + PREP_BLKS) {
    const int b = bid - TR_BLKS;
    const int ri = rel[b];
    if (t < NB)
      attb[b * 32 + t] = tanhf(rel_att[ri * NB + t] * (1.f / EMBR)) * PI_F;
    for (int i = t; i < DIM; i += 256) {
      const float ax = axis[(size_t)b * DIM + i];
      const float ag = argp[(size_t)b * DIM + i];
      Ebf[(size_t)b * D2 + i]       = f2bf(ax);
      Ebf[(size_t)b * D2 + DIM + i] = f2bf(ag);
      const float ra = rel_ax[(size_t)ri * DIM + i];
      const float rg = rel_ar[(size_t)ri * DIM + i];
      h0[(size_t)b * D2 + i] = f2bf(ax + tanhf(ra * (1.f / EMBR)) * PI_F);
      h0[(size_t)b * D2 + DIM + i] =
          f2bf(ag + tanhf(2.f * rg * (1.f / EMBR)) * (PI_F * 0.5f) + PI_F * 0.5f);
    }
  } else {
    int i = (bid - TR_BLKS - PREP_BLKS) * 256 + t;
    const float* s; ushort* d;
    if (i < W1F4) { s = W1; d = W1b; }
    else if ((i -= W1F4) < W2F4) { s = W2; d = W2b; }
    else if ((i -= W2F4) < W0F4) { s = W0; d = W0b; }
    else if ((i -= W0F4) < WA1F4) { s = Wa1; d = Wa1b; }
    else { i -= WA1F4; s = Wa2; d = Wa2b; }
    float4 v = ((const float4*)s)[i];
    ushort4 o;
    o.x = f2bf(v.x); o.y = f2bf(v.y); o.z = f2bf(v.z); o.w = f2bf(v.w);
    ((ushort4*)d)[i] = o;
  }
}

// ======= pipelined NT GEMM: C[m,n] = sum_k A[m,k]*Bt[n,k]; depth-3 prefetch =======
// EPI 1: bf16 out = relu(acc + bias[n]);  EPI 2: fp32 out = acc + bias[n]
template <int EPI>
__global__ __launch_bounds__(256, 2) void gemm_nt(
    const ushort* __restrict__ A, const ushort* __restrict__ Bt,
    const float* __restrict__ bias, float* __restrict__ Cf,
    ushort* __restrict__ Cb, int M, int N, int K) {
  __shared__ ushort As[4][128 * 32];
  __shared__ ushort Bs[4][128 * 32];
  const int tid  = threadIdx.x;
  const int lane = tid & 63, wave = tid >> 6;
  const int wm = wave >> 1, wn = wave & 1;
  const int lrow = lane & 15, quad = lane >> 4;
  const int m0 = blockIdx.y * 128, n0 = blockIdx.x * 128;
  const int T = K >> 5;

  const int rr = lane >> 2;
  const int eo = (lane & 3) * 8;
  const int c1 = wave, c2 = wave + 4;
  const ushort* Ag1 = A  + (size_t)(m0 + c1 * 16 + rr) * K + eo;
  const ushort* Ag2 = A  + (size_t)(m0 + c2 * 16 + rr) * K + eo;
  const ushort* Bg1 = Bt + (size_t)(n0 + c1 * 16 + rr) * K + eo;
  const ushort* Bg2 = Bt + (size_t)(n0 + c2 * 16 + rr) * K + eo;

  auto issue = [&](int slot) {
    const int t  = (slot < T - 1) ? slot : T - 1;
    const int bf = slot & 3;
    const int kk = t << 5;
    gld_lds16(Ag1 + kk, &As[bf][c1 * 512]);
    gld_lds16(Ag2 + kk, &As[bf][c2 * 512]);
    gld_lds16(Bg1 + kk, &Bs[bf][c1 * 512]);
    gld_lds16(Bg2 + kk, &Bs[bf][c2 * 512]);
  };

  f32x4 acc[4][4] = {};
  issue(0); issue(1); issue(2);

  for (int t = 0; t < T; ++t) {
    WAITVM(8);                          // tile t's 4 loads done; 2 batches in flight
    __builtin_amdgcn_s_barrier();
    issue(t + 3);
    const ushort* as = As[t & 3];
    const ushort* bs = Bs[t & 3];
    short8 af[4], bq[4];
#pragma unroll
    for (int i = 0; i < 4; ++i) {
      af[i] = *(const short8*)&as[(wm * 64 + i * 16 + lrow) * 32 + quad * 8];
      bq[i] = *(const short8*)&bs[(wn * 64 + i * 16 + lrow) * 32 + quad * 8];
    }
#pragma unroll
    for (int mi = 0; mi < 4; ++mi)
#pragma unroll
      for (int ni = 0; ni < 4; ++ni)
        acc[mi][ni] = __builtin_amdgcn_mfma_f32_16x16x32_bf16(
            af[mi], bq[ni], acc[mi][ni], 0, 0, 0);
  }
  WAITVM(0);                            // drain clamped prefetches before LDS dealloc

  const int colBase = n0 + wn * 64;
  const int rowBase = m0 + wm * 64;
#pragma unroll
  for (int mi = 0; mi < 4; ++mi) {
#pragma unroll
    for (int ni = 0; ni < 4; ++ni) {
      const int col  = colBase + ni * 16 + lrow;
      const int row0 = rowBase + mi * 16 + quad * 4;
      const float bv = bias[col];
      if (EPI == 1) {
#pragma unroll
        for (int g = 0; g < 4; ++g)
          Cb[(size_t)(row0 + g) * N + col] = f2bf(fmaxf(acc[mi][ni][g] + bv, 0.f));
      } else {
#pragma unroll
        for (int g = 0; g < 4; ++g)
          Cf[(size_t)(row0 + g) * N + col] = acc[mi][ni][g] + bv;
      }
    }
  }
}

// ==== rtrans GEMM v6: i-outer / r-inner, A-resident regs + sched_barrier fences ====
// out[b,o] partial over i-chunk z: sum_r att[b,r] * sum_{i in z} E[b,i]*RB[r,i,o].
// RACE FIX (rule #18 class): raw s_barrier + s_waitcnt builtins are IntrNoMem ->
// plain LDS loads (bq ds_reads) could be software-pipelined ACROSS them by the
// scheduler, reading buffer v%3 before slot v's global_load_lds landed (rt3/4/5
// failures: 0.31/0.37/0.42, run-varying = timing race). sched_barrier(0) after
// each barrier and at each step end pins every step's memory ops inside its
// wait window. af held in VGPRs across all r -> loop LDS reads halve (4xb128).
__global__ __launch_bounds__(256, 2) void gemm_rt6(
    const ushort* __restrict__ E,    // (1024 x 1024) bf16
    const ushort* __restrict__ RBt,  // (1024 x 30720) bf16; row o, col k=r*1024+i
    const float* __restrict__ attb,  // (B, 32)
    float* __restrict__ C1p) {       // (NZ, 1024, 1024) fp32 partials
  __shared__ ushort Bs[3][128 * 32];   // 24 KB ring
  __shared__ ushort As[4][128 * 32];   // 32 KB, staged once (sub-tile ks = k-cols ks*32..+32)
  __shared__ float attL[NB * 128];     // 15 KB, [r][row]
  const int tid  = threadIdx.x;
  const int lane = tid & 63, wave = tid >> 6;
  const int wm = wave >> 1, wn = wave & 1;
  const int lrow = lane & 15, quad = lane >> 4;
  const int n0 = blockIdx.x * 128, m0 = blockIdx.y * 128, z = blockIdx.z;

  const int rr = lane >> 2;
  const int eo = (lane & 3) * 8;

  // --- A stage: 8 gld_lds per wave; sub-tile ks, 64-row half j; 16 rows x 32 cols each ---
#pragma unroll
  for (int j = 0; j < 2; ++j)
#pragma unroll
    for (int ks = 0; ks < 4; ++ks)
      gld_lds16(E + (size_t)(m0 + j * 64 + wave * 16 + rr) * D2 + z * 128 + ks * 32 + eo,
                &As[ks][(j * 64 + wave * 16) * 32]);

  // --- B ring: 2 gld_lds per slot per wave (rows wave*16.. and 64+wave*16..) ---
  const ushort* Bg1 = RBt + (size_t)(n0 + wave * 16 + rr) * K1 + z * 128 + eo;
  const ushort* Bg2 = Bg1 + (size_t)64 * K1;
  auto issue = [&](int slot) {
    const int v  = (slot < 120) ? slot : 119;  // clamp keeps vmcnt bookkeeping exact
    const int bf = slot % 3;
    const size_t ko = (size_t)(v >> 2) * 1024 + (v & 3) * 32;  // r*1024 + ks*32
    gld_lds16(Bg1 + ko, &Bs[bf][(wave * 16) * 32]);
    gld_lds16(Bg2 + ko, &Bs[bf][(64 + wave * 16) * 32]);
  };
  issue(0); issue(1);

  // --- att -> LDS transposed [r][row] (round-0 exact staging pattern) ---
  for (int idx = tid; idx < NB * 128; idx += 256)
    attL[idx] = attb[(size_t)(m0 + (idx & 127)) * 32 + (idx >> 7)];

  __syncthreads();   // FULL drain (vmcnt 0 + lgkm 0) + fence + barrier

  short8 af[4][4];                     // A-fragments, resident across all r
#pragma unroll
  for (int ks = 0; ks < 4; ++ks)
#pragma unroll
    for (int mi = 0; mi < 4; ++mi)
      af[ks][mi] = *(const short8*)&As[ks][(wm * 64 + mi * 16 + lrow) * 32 + quad * 8];

  f32x4 acc[4][4]  = {};
  f32x4 acc2[4][4] = {};

  for (int r = 0; r < NB; ++r) {
#pragma unroll
    for (int ks = 0; ks < 4; ++ks) {
      const int v = r * 4 + ks;
      WAITVM(2);                       // slot v retired (no-op for v<2: pre-drained)
      __builtin_amdgcn_s_barrier();
      SCHED_FENCE();                   // nothing (esp. bq ds_reads) hoists above wait+barrier
      issue(v + 2);                    // writes buf (v+2)%3: != read v%3, != inflight (v+1)%3
      const ushort* bs = Bs[v % 3];
      short8 bq[4];
#pragma unroll
      for (int i = 0; i < 4; ++i)
        bq[i] = *(const short8*)&bs[(wn * 64 + i * 16 + lrow) * 32 + quad * 8];
#pragma unroll
      for (int mi = 0; mi < 4; ++mi)
#pragma unroll
        for (int ni = 0; ni < 4; ++ni)
          acc[mi][ni] = __builtin_amdgcn_mfma_f32_16x16x32_bf16(
              af[ks][mi], bq[ni], acc[mi][ni], 0, 0, 0);
      SCHED_FENCE();                   // nothing sinks out of this step either
    }
    // fold: acc2 += att[row, r] * acc; acc = 0   (round-0 exact scalar pattern)
#pragma unroll
    for (int mi = 0; mi < 4; ++mi)
#pragma unroll
      for (int g = 0; g < 4; ++g) {
        const float s = attL[r * 128 + wm * 64 + mi * 16 + quad * 4 + g];
#pragma unroll
        for (int ni = 0; ni < 4; ++ni) {
          acc2[mi][ni][g] += s * acc[mi][ni][g];
          acc[mi][ni][g] = 0.f;
        }
      }
  }
  WAITVM(0);                           // drain clamped prefetches before LDS dealloc

  float* dst = C1p + (size_t)z * BATCH * D2;
  const int colBase = n0 + wn * 64;
  const int rowBase = m0 + wm * 64;
#pragma unroll
  for (int mi = 0; mi < 4; ++mi)
#pragma unroll
    for (int ni = 0; ni < 4; ++ni) {
      const int col  = colBase + ni * 16 + lrow;
      const int row0 = rowBase + mi * 16 + quad * 4;
#pragma unroll
      for (int g = 0; g < 4; ++g)
        dst[(size_t)(row0 + g) * D2 + col] = acc2[mi][ni][g];
    }
}

// ------- reduce slices + att@rel_bias + LayerNorm -> xrt (fp32), Xb row (bf16) -------
__global__ __launch_bounds__(256) void reduce_ln_rt(
    const float* __restrict__ C1p, const float* __restrict__ att,
    const float* __restrict__ rel_bias, float* __restrict__ xf,
    ushort* __restrict__ Xb) {
  const int b = blockIdx.x, t = threadIdx.x;
  __shared__ float attS[NB];
  __shared__ float sa[4], sb[4];
  if (t < NB) attS[t] = att[b * 32 + t];
  __syncthreads();
  float v[4], sum = 0.f, sq = 0.f;
#pragma unroll
  for (int j = 0; j < 4; ++j) {
    const int o = j * 256 + t;
    float acc = 0.f;
#pragma unroll
    for (int s = 0; s < NZ; ++s)
      acc += C1p[((size_t)s * BATCH + b) * D2 + o];
    float bias = 0.f;
    for (int r = 0; r < NB; ++r) bias += attS[r] * rel_bias[r * D2 + o];
    acc += bias;
    v[j] = acc; sum += acc; sq += acc * acc;
  }
  const int lane = t & 63, wv = t >> 6;
  for (int off = 32; off > 0; off >>= 1) {
    sum += __shfl_down(sum, off, 64);
    sq  += __shfl_down(sq, off, 64);
  }
  if (lane == 0) { sa[wv] = sum; sb[wv] = sq; }
  __syncthreads();
  const float S = sa[0] + sa[1] + sa[2] + sa[3];
  const float Q = sb[0] + sb[1] + sb[2] + sb[3];
  const float mean = S / D2;
  const float inv = rsqrtf(fmaxf(Q / D2 - mean * mean, 0.f) + 1e-5f);
#pragma unroll
  for (int j = 0; j < 4; ++j) {
    const int o = j * 256 + t;
    const float y = (v[j] - mean) * inv;
    xf[(size_t)b * D2 + o] = y;
    Xb[(size_t)b * D2 + o] = f2bf(y);
  }
}

// ---------------- row LayerNorm (mlp branch) ----------------
__global__ __launch_bounds__(256) void ln_rows(
    const float* __restrict__ G, float* __restrict__ xf, ushort* __restrict__ Xb) {
  const int b = blockIdx.x, t = threadIdx.x;
  __shared__ float sa[4], sb[4];
  float v[4], sum = 0.f, sq = 0.f;
#pragma unroll
  for (int j = 0; j < 4; ++j) {
    const int o = j * 256 + t;
    v[j] = G[(size_t)b * D2 + o];
    sum += v[j]; sq += v[j] * v[j];
  }
  const int lane = t & 63, wv = t >> 6;
  for (int off = 32; off > 0; off >>= 1) {
    sum += __shfl_down(sum, off, 64);
    sq  += __shfl_down(sq, off, 64);
  }
  if (lane == 0) { sa[wv] = sum; sb[wv] = sq; }
  __syncthreads();
  const float S = sa[0] + sa[1] + sa[2] + sa[3];
  const float Q = sb[0] + sb[1] + sb[2] + sb[3];
  const float mean = S / D2;
  const float inv = rsqrtf(fmaxf(Q / D2 - mean * mean, 0.f) + 1e-5f);
#pragma unroll
  for (int j = 0; j < 4; ++j) {
    const int o = j * 256 + t;
    const float y = (v[j] - mean) * inv;
    xf[(size_t)b * D2 + o] = y;
    Xb[(size_t)b * D2 + o] = f2bf(y);
  }
}

// -------- softmax over 2 branches + merge + final activations -> out (fp32) --------
__global__ __launch_bounds__(256) void fuse_out(
    const float* __restrict__ L, const float* __restrict__ xrt,
    const float* __restrict__ xml, float* __restrict__ out) {
  const int b = blockIdx.x, t = threadIdx.x;
#pragma unroll
  for (int j = 0; j < 4; ++j) {
    const int o = j * 256 + t;
    const float l0 = L[(size_t)b * D2 + o];
    const float l1 = L[(size_t)(BATCH + b) * D2 + o];
    const float w0 = 1.f / (1.f + expf(l1 - l0));
    const float m = w0 * xrt[(size_t)b * D2 + o] +
                    (1.f - w0) * xml[(size_t)b * D2 + o];
    if (o < DIM)
      out[(size_t)b * DIM + o] = tanhf(m) * PI_F;
    else
      out[(size_t)BATCH * DIM + (size_t)b * DIM + (o - DIM)] =
          tanhf(2.f * m) * (PI_F * 0.5f) + PI_F * 0.5f;
  }
}

extern "C" void kernel_launch(void* const* d_in, const int* in_sizes, int n_in,
                              void* d_out, int out_size, void* d_ws, size_t ws_size,
                              hipStream_t stream) {
  (void)in_sizes; (void)n_in; (void)out_size; (void)ws_size;
  const float* s_axis   = (const float*)d_in[0];
  const float* s_arg    = (const float*)d_in[1];
  const int*   rel      = (const int*)d_in[2];
  const float* rel_base = (const float*)d_in[3];
  const float* rel_att  = (const float*)d_in[4];
  const float* rel_bias = (const float*)d_in[5];
  const float* rel_ax_e = (const float*)d_in[6];
  const float* rel_ar_e = (const float*)d_in[7];
  const float* W1 = (const float*)d_in[8];
  const float* b1 = (const float*)d_in[9];
  const float* W2 = (const float*)d_in[10];
  const float* b2 = (const float*)d_in[11];
  const float* W0 = (const float*)d_in[12];
  const float* b0 = (const float*)d_in[13];
  const float* Wa1 = (const float*)d_in[14];
  const float* ba1 = (const float*)d_in[15];
  const float* Wa2 = (const float*)d_in[16];
  const float* ba2 = (const float*)d_in[17];

  char* ws = (char*)d_ws;
  size_t off = 0;
  ushort* RBt  = (ushort*)(ws + off); off += (size_t)K1 * D2 * 2;            // 63 MB
  float*  C1p  = (float*)(ws + off);  off += (size_t)NZ * BATCH * D2 * 4;    // 33.5 MB
  ushort* Ebf  = (ushort*)(ws + off); off += (size_t)BATCH * D2 * 2;
  ushort* W1b  = (ushort*)(ws + off); off += (size_t)HID * D2 * 2;
  ushort* W2b  = (ushort*)(ws + off); off += (size_t)HID * HID * 2;
  ushort* W0b  = (ushort*)(ws + off); off += (size_t)D2 * HID * 2;
  ushort* Wa1b = (ushort*)(ws + off); off += (size_t)DIM * D2 * 2;
  ushort* Wa2b = (ushort*)(ws + off); off += (size_t)D2 * DIM * 2;
  ushort* h0   = (ushort*)(ws + off); off += (size_t)BATCH * D2 * 2;
  ushort* Xb   = (ushort*)(ws + off); off += (size_t)2 * BATCH * D2 * 2;
  float*  xrt  = (float*)(ws + off);  off += (size_t)BATCH * D2 * 4;
  float*  xml  = (float*)(ws + off);  off += (size_t)BATCH * D2 * 4;
  float*  attb = (float*)(ws + off);  off += (size_t)BATCH * 32 * 4;
  // late buffers alias C1p (dead after reduce_ln_rt); 22 MB <= 33.5 MB
  char* ali = (char*)C1p;
  ushort* H1  = (ushort*)ali; ali += (size_t)BATCH * HID * 2;
  ushort* H2  = (ushort*)ali; ali += (size_t)BATCH * HID * 2;
  float*  G0  = (float*)ali;  ali += (size_t)BATCH * D2 * 4;
  ushort* Aat = (ushort*)ali; ali += (size_t)2 * BATCH * DIM * 2;
  float*  Lg  = (float*)ali;  ali += (size_t)2 * BATCH * D2 * 4;

  mega_prep<<<TR_BLKS + PREP_BLKS + CVT_BLKS, 256, 0, stream>>>(
      rel_base, RBt, s_axis, s_arg, rel, rel_att, rel_ax_e, rel_ar_e,
      attb, Ebf, h0, W1, W2, W0, Wa1, Wa2, W1b, W2b, W0b, Wa1b, Wa2b);
  gemm_rt6<<<dim3(D2 / 128, BATCH / 128, NZ), 256, 0, stream>>>(
      Ebf, RBt, attb, C1p);
  reduce_ln_rt<<<BATCH, 256, 0, stream>>>(C1p, attb, rel_bias, xrt, Xb);
  gemm_nt<1><<<dim3(HID / 128, BATCH / 128), 256, 0, stream>>>(
      h0, W1b, b1, nullptr, H1, BATCH, HID, D2);
  gemm_nt<1><<<dim3(HID / 128, BATCH / 128), 256, 0, stream>>>(
      H1, W2b, b2, nullptr, H2, BATCH, HID, HID);
  gemm_nt<2><<<dim3(D2 / 128, BATCH / 128), 256, 0, stream>>>(
      H2, W0b, b0, G0, nullptr, BATCH, D2, HID);
  ln_rows<<<BATCH, 256, 0, stream>>>(G0, xml, Xb + (size_t)BATCH * D2);
  gemm_nt<1><<<dim3(DIM / 128, 2 * BATCH / 128), 256, 0, stream>>>(
      Xb, Wa1b, ba1, nullptr, Aat, 2 * BATCH, DIM, D2);
  gemm_nt<2><<<dim3(D2 / 128, 2 * BATCH / 128), 256, 0, stream>>>(
      Aat, Wa2b, ba2, Lg, nullptr, 2 * BATCH, D2, DIM);
  fuse_out<<<BATCH, 256, 0, stream>>>(Lg, xrt, xml, (float*)d_out);
}